// Round 5
// baseline (1197.953 us; speedup 1.0000x reference)
//
#include <hip/hip_runtime.h>
#include <hip/hip_bf16.h>

#define N_NODES 100000
#define N_EDGES 3200000
#define N_GRAPHS 125
#define D 64
#define NB 200          // buckets
#define BW 500          // nodes per bucket (NB*BW == N_NODES)
#define CAP 20480       // max edges per bucket (mean 16000, sigma ~126)
#define EPW 16000       // edges per workgroup in bucket_scatter (NB wgs)

// ---------- CSR build (bucketed, LDS-atomic) ----------

__global__ void init_bcursor(int* __restrict__ bcursor) {
    int t = blockIdx.x * blockDim.x + threadIdx.x;
    if (t < NB) bcursor[t] = t * CAP;
}

// partition edges into NB dst-range buckets; writes (src,dst) pairs densely
__global__ void bucket_scatter(const int* __restrict__ src, const int* __restrict__ dst,
                               int* __restrict__ bcursor, int2* __restrict__ pairs) {
    __shared__ int bins[NB];
    int wg = blockIdx.x, t = threadIdx.x;
    int e0 = wg * EPW, e1 = e0 + EPW;
    if (t < NB) bins[t] = 0;
    __syncthreads();
    for (int i = e0 + t; i < e1; i += 256)
        atomicAdd(&bins[dst[i] / BW], 1);
    __syncthreads();
    if (t < NB) {
        int c = bins[t];
        bins[t] = c ? atomicAdd(&bcursor[t], c) : 0;
    }
    __syncthreads();
    for (int i = e0 + t; i < e1; i += 256) {
        int s = src[i], d = dst[i];
        int pos = atomicAdd(&bins[d / BW], 1);
        pairs[pos] = make_int2(s, d);
    }
}

// per-bucket node histogram -> cnt, dis
__global__ void bucket_hist(const int2* __restrict__ pairs, const int* __restrict__ bcursor,
                            int* __restrict__ cnt, float* __restrict__ dis) {
    __shared__ int h[BW];
    int b = blockIdx.x, t = threadIdx.x;
    for (int i = t; i < BW; i += 256) h[i] = 0;
    __syncthreads();
    int base = b * CAP, n = bcursor[b] - base;
    int nb = b * BW;
    for (int i = t; i < n; i += 256)
        atomicAdd(&h[pairs[base + i].y - nb], 1);
    __syncthreads();
    for (int i = t; i < BW; i += 256) {
        int c = h[i];
        cnt[nb + i] = c;
        dis[nb + i] = rsqrtf((float)c + 1.0f);
    }
}

// per-block sums of cnt
__global__ void scan1_kernel(const int* __restrict__ cnt, int* __restrict__ sums) {
    __shared__ int lds[256];
    int b = blockIdx.x, t = threadIdx.x;
    int base = b * BW;
    int s = 0;
    if (t < BW / 4) {
#pragma unroll
        for (int k = 0; k < 4; ++k) s += cnt[base + t * 4 + k];
    }
    lds[t] = s;
    __syncthreads();
    for (int off = 128; off > 0; off >>= 1) {
        if (t < off) lds[t] += lds[t + off];
        __syncthreads();
    }
    if (t == 0) sums[b] = lds[0];
}

// exclusive scan of NB block sums -> offs; seal row_start[N]
__global__ void scan2_kernel(const int* __restrict__ sums, int* __restrict__ offs,
                             int* __restrict__ row_start) {
    __shared__ int lds[256];
    int t = threadIdx.x;
    int own = (t < NB) ? sums[t] : 0;
    lds[t] = own;
    __syncthreads();
    for (int off = 1; off < 256; off <<= 1) {
        int v = (t >= off) ? lds[t - off] : 0;
        __syncthreads();
        lds[t] += v;
        __syncthreads();
    }
    if (t < NB) offs[t] = lds[t] - own;
    if (t == 0) row_start[N_NODES] = N_EDGES;
}

// within-block exclusive scan -> row_start
__global__ void scan3_kernel(const int* __restrict__ cnt, const int* __restrict__ offs,
                             int* __restrict__ row_start) {
    __shared__ int lds[256];
    int b = blockIdx.x, t = threadIdx.x;
    int base = b * BW;
    int local[4];
    int s = 0;
    if (t < BW / 4) {
#pragma unroll
        for (int k = 0; k < 4; ++k) { local[k] = cnt[base + t * 4 + k]; s += local[k]; }
    }
    lds[t] = s;
    __syncthreads();
    for (int off = 1; off < 256; off <<= 1) {
        int v = (t >= off) ? lds[t - off] : 0;
        __syncthreads();
        lds[t] += v;
        __syncthreads();
    }
    if (t < BW / 4) {
        int pre = lds[t] - s + offs[b];
#pragma unroll
        for (int k = 0; k < 4; ++k) {
            row_start[base + t * 4 + k] = pre;
            pre += local[k];
        }
    }
}

// per-bucket CSR fill with LDS cursors
__global__ void bucket_fill(const int2* __restrict__ pairs, const int* __restrict__ bcursor,
                            const int* __restrict__ row_start, int* __restrict__ csr) {
    __shared__ int cur[BW];
    int b = blockIdx.x, t = threadIdx.x;  // 512 threads
    int nb = b * BW;
    for (int i = t; i < BW; i += 512) cur[i] = row_start[nb + i];
    __syncthreads();
    int base = b * CAP, n = bcursor[b] - base;
    for (int i = t; i < n; i += 512) {
        int2 p = pairs[base + i];
        int pos = atomicAdd(&cur[p.y - nb], 1);
        csr[pos] = p.x;
    }
}

// ---------- compute ----------

// Y = X @ W (+bias). block 256 = 4 waves, each wave does 4 rows x 64 cols.
// Row indices for loads are CLAMPED to nrows-1 (no reliance on padding);
// stores are guarded.
__global__ void gemm_kernel(const float* __restrict__ X, const float* __restrict__ W,
                            const float* __restrict__ bias, float* __restrict__ Y,
                            int nrows) {
    __shared__ float Ws[64][64];
    for (int i = threadIdx.x; i < 64 * 64; i += 256)
        Ws[i >> 6][i & 63] = W[i];
    __syncthreads();
    int c  = threadIdx.x & 63;
    int q  = threadIdx.x >> 6;           // wave 0..3
    int r0 = blockIdx.x * 16 + q * 4;
    if (r0 >= nrows) return;
    int r1 = min(r0 + 1, nrows - 1);
    int r2 = min(r0 + 2, nrows - 1);
    int r3 = min(r0 + 3, nrows - 1);
    const float* x0 = X + (size_t)r0 * D;
    const float* x1 = X + (size_t)r1 * D;
    const float* x2 = X + (size_t)r2 * D;
    const float* x3 = X + (size_t)r3 * D;
    float b0 = bias ? bias[c] : 0.0f;
    float acc0 = b0, acc1 = b0, acc2 = b0, acc3 = b0;
#pragma unroll
    for (int k = 0; k < 64; k += 4) {
        float4 a0 = *(const float4*)(x0 + k);
        float4 a1 = *(const float4*)(x1 + k);
        float4 a2 = *(const float4*)(x2 + k);
        float4 a3 = *(const float4*)(x3 + k);
        float w0 = Ws[k][c], w1 = Ws[k + 1][c], w2 = Ws[k + 2][c], w3 = Ws[k + 3][c];
        acc0 = fmaf(a0.x, w0, acc0); acc0 = fmaf(a0.y, w1, acc0);
        acc0 = fmaf(a0.z, w2, acc0); acc0 = fmaf(a0.w, w3, acc0);
        acc1 = fmaf(a1.x, w0, acc1); acc1 = fmaf(a1.y, w1, acc1);
        acc1 = fmaf(a1.z, w2, acc1); acc1 = fmaf(a1.w, w3, acc1);
        acc2 = fmaf(a2.x, w0, acc2); acc2 = fmaf(a2.y, w1, acc2);
        acc2 = fmaf(a2.z, w2, acc2); acc2 = fmaf(a2.w, w3, acc2);
        acc3 = fmaf(a3.x, w0, acc3); acc3 = fmaf(a3.y, w1, acc3);
        acc3 = fmaf(a3.z, w2, acc3); acc3 = fmaf(a3.w, w3, acc3);
    }
    Y[(size_t)r0 * D + c] = acc0;
    if (r0 + 1 < nrows) Y[(size_t)(r0 + 1) * D + c] = acc1;
    if (r0 + 2 < nrows) Y[(size_t)(r0 + 2) * D + c] = acc2;
    if (r0 + 3 < nrows) Y[(size_t)(r0 + 3) * D + c] = acc3;
}

// one wave per dst node; half-wave (32 lanes, float2/lane) per edge ->
// 2 edges per iteration, one dwordx2 load instruction covers both rows.
__global__ void gather_kernel(const float* __restrict__ H, const int* __restrict__ csr,
                              const int* __restrict__ row_start, const float* __restrict__ dis,
                              const float* __restrict__ bias, float* __restrict__ Bout,
                              int do_relu) {
    int v    = (blockIdx.x * blockDim.x + threadIdx.x) >> 6;
    int lane = threadIdx.x & 63;
    int half = lane >> 5;                 // 0 or 1
    int l32  = lane & 31;
    if (v >= N_NODES) return;
    int base = row_start[v];
    int n = row_start[v + 1] - base;
    float disv = dis[v];
    const float2* H2 = (const float2*)H;

    // acc covers feats {2*l32, 2*l32+1}; half 0 seeds bias + self-loop, half 1 zero
    float2 acc = make_float2(0.0f, 0.0f);
    if (half == 0) {
        float2 hv = H2[(size_t)v * 32 + l32];
        acc.x = fmaf(hv.x, disv * disv, bias[2 * l32]);
        acc.y = fmaf(hv.y, disv * disv, bias[2 * l32 + 1]);
    }

    for (int c = 0; c < n; c += 64) {
        int m = min(64, n - c);
        int sl = 0; float dl = 0.0f;
        if (lane < m) { sl = csr[base + c + lane]; dl = dis[sl]; }
        int mp = (m + 1) >> 1;
#pragma unroll 4
        for (int t = 0; t < mp; ++t) {
            int eidx = 2 * t + half;               // lanes >= m preloaded {0, 0.0} -> contribute 0
            int ssrc  = __shfl(sl, eidx);
            float nrm = __shfl(dl, eidx) * disv;
            float2 hv = H2[(size_t)ssrc * 32 + l32];
            acc.x = fmaf(hv.x, nrm, acc.x);
            acc.y = fmaf(hv.y, nrm, acc.y);
        }
    }
    // cross-half reduce
    acc.x += __shfl_xor(acc.x, 32);
    acc.y += __shfl_xor(acc.y, 32);
    if (half == 0) {
        if (do_relu) { acc.x = fmaxf(acc.x, 0.0f); acc.y = fmaxf(acc.y, 0.0f); }
        ((float2*)Bout)[(size_t)v * 32 + l32] = acc;
    }
}

// one block per graph: mean over contiguous node segment [ptr[g], ptr[g+1])
__global__ void pool_kernel(const float* __restrict__ H, const int* __restrict__ ptr,
                            float* __restrict__ out) {
    int g = blockIdx.x;
    int start = ptr[g], end = ptr[g + 1];
    int lane  = threadIdx.x & 63;
    int chunk = threadIdx.x >> 6;
    float acc = 0.0f;
    for (int r = start + chunk; r < end; r += 4)
        acc += H[(size_t)r * D + lane];
    __shared__ float tmp[4][64];
    tmp[chunk][lane] = acc;
    __syncthreads();
    if (threadIdx.x < 64) {
        float s = tmp[0][lane] + tmp[1][lane] + tmp[2][lane] + tmp[3][lane];
        out[g * D + lane] = s / (float)(end - start);
    }
}

extern "C" void kernel_launch(void* const* d_in, const int* in_sizes, int n_in,
                              void* d_out, int out_size, void* d_ws, size_t ws_size,
                              hipStream_t stream) {
    const float* x   = (const float*)d_in[0];
    const int*   ei  = (const int*)d_in[1];
    const int*   src = ei;
    const int*   dst = ei + N_EDGES;
    const int*   ptr = (const int*)d_in[2];
    const float* W1  = (const float*)d_in[3];
    const float* b1  = (const float*)d_in[4];
    const float* W2  = (const float*)d_in[5];
    const float* b2  = (const float*)d_in[6];
    const float* Wf  = (const float*)d_in[7];
    const float* bfp = (const float*)d_in[8];
    float* out = (float*)d_out;

    // workspace layout (4-byte units)
    int*   cnt       = (int*)d_ws;                  // 100352
    int*   row_start = cnt + 100352;                // 100352 (N+1 used)
    int*   sums      = row_start + 100352;          // 256
    int*   offs      = sums + 256;                  // 256
    int*   bcursor   = offs + 256;                  // 256
    float* P         = (float*)(bcursor + 256);     // 8192 (125*64 used)
    float* dis       = P + 8192;                    // 100352
    int*   csr       = (int*)(dis + 100352);        // 3200000
    float* A         = (float*)(csr + 3200000);     // 6400000
    float* B         = A + (size_t)N_NODES * D;     // 6400000
    int2*  pairs     = (int2*)A;                    // NB*CAP int2, aliases A+B

    // --- CSR build ---
    init_bcursor<<<1, 256, 0, stream>>>(bcursor);
    bucket_scatter<<<NB, 256, 0, stream>>>(src, dst, bcursor, pairs);
    bucket_hist<<<NB, 256, 0, stream>>>(pairs, bcursor, cnt, dis);
    scan1_kernel<<<NB, 256, 0, stream>>>(cnt, sums);
    scan2_kernel<<<1, 256, 0, stream>>>(sums, offs, row_start);
    scan3_kernel<<<NB, 256, 0, stream>>>(cnt, offs, row_start);
    bucket_fill<<<NB, 512, 0, stream>>>(pairs, bcursor, row_start, csr);

    const int grid_gather = (N_NODES + 3) / 4;      // 4 waves/block, 1 node/wave
    const int grid_gemm   = (N_NODES + 15) / 16;    // 16 rows/block

    // layer 1
    gemm_kernel<<<grid_gemm, 256, 0, stream>>>(x, W1, nullptr, A, N_NODES);
    gather_kernel<<<grid_gather, 256, 0, stream>>>(A, csr, row_start, dis, b1, B, 1);

    // layer 2
    gemm_kernel<<<grid_gemm, 256, 0, stream>>>(B, W2, nullptr, A, N_NODES);
    gather_kernel<<<grid_gather, 256, 0, stream>>>(A, csr, row_start, dis, b2, B, 1);

    // head: pool first (mean commutes with linear head), then tiny GEMM
    pool_kernel<<<N_GRAPHS, 256, 0, stream>>>(B, ptr, P);
    gemm_kernel<<<(N_GRAPHS + 15) / 16, 256, 0, stream>>>(P, Wf, bfp, out, N_GRAPHS);
}

// Round 6
// 616.019 us; speedup vs baseline: 1.9447x; 1.9447x over previous
//
#include <hip/hip_runtime.h>
#include <hip/hip_bf16.h>

#define N_NODES 100000
#define N_EDGES 3200000
#define N_GRAPHS 125
#define D 64
#define NB 200          // buckets
#define BW 500          // nodes per bucket (NB*BW == N_NODES)
#define CAP 20480       // max edges per bucket (mean 16000, sigma ~126)
#define EPW 16000       // edges per workgroup in bucket_scatter (NB wgs)

// ---------- CSR build (bucketed, LDS-atomic) ----------

__global__ void init_bcursor(int* __restrict__ bcursor) {
    int t = blockIdx.x * blockDim.x + threadIdx.x;
    if (t < NB) bcursor[t] = t * CAP;
}

// partition edges into NB dst-range buckets; writes (src,dst) pairs densely
__global__ void bucket_scatter(const int* __restrict__ src, const int* __restrict__ dst,
                               int* __restrict__ bcursor, int2* __restrict__ pairs) {
    __shared__ int bins[NB];
    int wg = blockIdx.x, t = threadIdx.x;
    int e0 = wg * EPW, e1 = e0 + EPW;
    if (t < NB) bins[t] = 0;
    __syncthreads();
    for (int i = e0 + t; i < e1; i += 256)
        atomicAdd(&bins[dst[i] / BW], 1);
    __syncthreads();
    if (t < NB) {
        int c = bins[t];
        bins[t] = c ? atomicAdd(&bcursor[t], c) : 0;
    }
    __syncthreads();
    for (int i = e0 + t; i < e1; i += 256) {
        int s = src[i], d = dst[i];
        int pos = atomicAdd(&bins[d / BW], 1);
        pairs[pos] = make_int2(s, d);
    }
}

// per-bucket node histogram -> cnt, dis
__global__ void bucket_hist(const int2* __restrict__ pairs, const int* __restrict__ bcursor,
                            int* __restrict__ cnt, float* __restrict__ dis) {
    __shared__ int h[BW];
    int b = blockIdx.x, t = threadIdx.x;
    for (int i = t; i < BW; i += 256) h[i] = 0;
    __syncthreads();
    int base = b * CAP, n = bcursor[b] - base;
    int nb = b * BW;
    for (int i = t; i < n; i += 256)
        atomicAdd(&h[pairs[base + i].y - nb], 1);
    __syncthreads();
    for (int i = t; i < BW; i += 256) {
        int c = h[i];
        cnt[nb + i] = c;
        dis[nb + i] = rsqrtf((float)c + 1.0f);
    }
}

// per-block sums of cnt
__global__ void scan1_kernel(const int* __restrict__ cnt, int* __restrict__ sums) {
    __shared__ int lds[256];
    int b = blockIdx.x, t = threadIdx.x;
    int base = b * BW;
    int s = 0;
    if (t < BW / 4) {
#pragma unroll
        for (int k = 0; k < 4; ++k) s += cnt[base + t * 4 + k];
    }
    lds[t] = s;
    __syncthreads();
    for (int off = 128; off > 0; off >>= 1) {
        if (t < off) lds[t] += lds[t + off];
        __syncthreads();
    }
    if (t == 0) sums[b] = lds[0];
}

// exclusive scan of NB block sums -> offs; seal row_start[N]
__global__ void scan2_kernel(const int* __restrict__ sums, int* __restrict__ offs,
                             int* __restrict__ row_start) {
    __shared__ int lds[256];
    int t = threadIdx.x;
    int own = (t < NB) ? sums[t] : 0;
    lds[t] = own;
    __syncthreads();
    for (int off = 1; off < 256; off <<= 1) {
        int v = (t >= off) ? lds[t - off] : 0;
        __syncthreads();
        lds[t] += v;
        __syncthreads();
    }
    if (t < NB) offs[t] = lds[t] - own;
    if (t == 0) row_start[N_NODES] = N_EDGES;
}

// within-block exclusive scan -> row_start
__global__ void scan3_kernel(const int* __restrict__ cnt, const int* __restrict__ offs,
                             int* __restrict__ row_start) {
    __shared__ int lds[256];
    int b = blockIdx.x, t = threadIdx.x;
    int base = b * BW;
    int local[4];
    int s = 0;
    if (t < BW / 4) {
#pragma unroll
        for (int k = 0; k < 4; ++k) { local[k] = cnt[base + t * 4 + k]; s += local[k]; }
    }
    lds[t] = s;
    __syncthreads();
    for (int off = 1; off < 256; off <<= 1) {
        int v = (t >= off) ? lds[t - off] : 0;
        __syncthreads();
        lds[t] += v;
        __syncthreads();
    }
    if (t < BW / 4) {
        int pre = lds[t] - s + offs[b];
#pragma unroll
        for (int k = 0; k < 4; ++k) {
            row_start[base + t * 4 + k] = pre;
            pre += local[k];
        }
    }
}

// per-bucket CSR fill with LDS cursors
__global__ void bucket_fill(const int2* __restrict__ pairs, const int* __restrict__ bcursor,
                            const int* __restrict__ row_start, int* __restrict__ csr) {
    __shared__ int cur[BW];
    int b = blockIdx.x, t = threadIdx.x;  // 512 threads
    int nb = b * BW;
    for (int i = t; i < BW; i += 512) cur[i] = row_start[nb + i];
    __syncthreads();
    int base = b * CAP, n = bcursor[b] - base;
    for (int i = t; i < n; i += 512) {
        int2 p = pairs[base + i];
        int pos = atomicAdd(&cur[p.y - nb], 1);
        csr[pos] = p.x;
    }
}

// ---------- compute ----------

// Y[r][c] = sum_k X[r][k] * W[k][c] (+ bias[c] if bias != nullptr)
// EXACT R3 version (proven ~fast): block = 256 threads -> 4 rows x 64 cols.
__global__ void gemm_kernel(const float* __restrict__ X, const float* __restrict__ W,
                            const float* __restrict__ bias, float* __restrict__ Y,
                            int nrows) {
    __shared__ float Ws[64][64];
    for (int i = threadIdx.x; i < 64 * 64; i += 256)
        Ws[i >> 6][i & 63] = W[i];
    __syncthreads();
    int c  = threadIdx.x & 63;
    int rl = threadIdx.x >> 6;  // 0..3
    int r  = blockIdx.x * 4 + rl;
    if (r < nrows) {
        const float* xr = X + (size_t)r * D;
        float acc = bias ? bias[c] : 0.0f;
#pragma unroll
        for (int k = 0; k < 64; ++k)
            acc = fmaf(xr[k], Ws[k][c], acc);
        Y[(size_t)r * D + c] = acc;
    }
}

// one wave per dst node; half-wave (32 lanes, float2/lane) per edge ->
// 2 edges per iteration, one dwordx2 load instruction covers both rows.
__global__ void gather_kernel(const float* __restrict__ H, const int* __restrict__ csr,
                              const int* __restrict__ row_start, const float* __restrict__ dis,
                              const float* __restrict__ bias, float* __restrict__ Bout,
                              int do_relu) {
    int v    = (blockIdx.x * blockDim.x + threadIdx.x) >> 6;
    int lane = threadIdx.x & 63;
    int half = lane >> 5;                 // 0 or 1
    int l32  = lane & 31;
    if (v >= N_NODES) return;
    int base = row_start[v];
    int n = row_start[v + 1] - base;
    float disv = dis[v];
    const float2* H2 = (const float2*)H;

    // acc covers feats {2*l32, 2*l32+1}; half 0 seeds bias + self-loop, half 1 zero
    float2 acc = make_float2(0.0f, 0.0f);
    if (half == 0) {
        float2 hv = H2[(size_t)v * 32 + l32];
        acc.x = fmaf(hv.x, disv * disv, bias[2 * l32]);
        acc.y = fmaf(hv.y, disv * disv, bias[2 * l32 + 1]);
    }

    for (int c = 0; c < n; c += 64) {
        int m = min(64, n - c);
        int sl = 0; float dl = 0.0f;
        if (lane < m) { sl = csr[base + c + lane]; dl = dis[sl]; }
        int mp = (m + 1) >> 1;
#pragma unroll 4
        for (int t = 0; t < mp; ++t) {
            int eidx = 2 * t + half;               // lanes >= m preloaded {0, 0.0} -> contribute 0
            int ssrc  = __shfl(sl, eidx);
            float nrm = __shfl(dl, eidx) * disv;
            float2 hv = H2[(size_t)ssrc * 32 + l32];
            acc.x = fmaf(hv.x, nrm, acc.x);
            acc.y = fmaf(hv.y, nrm, acc.y);
        }
    }
    // cross-half reduce
    acc.x += __shfl_xor(acc.x, 32);
    acc.y += __shfl_xor(acc.y, 32);
    if (half == 0) {
        if (do_relu) { acc.x = fmaxf(acc.x, 0.0f); acc.y = fmaxf(acc.y, 0.0f); }
        ((float2*)Bout)[(size_t)v * 32 + l32] = acc;
    }
}

// one block per graph: mean over contiguous node segment [ptr[g], ptr[g+1])
__global__ void pool_kernel(const float* __restrict__ H, const int* __restrict__ ptr,
                            float* __restrict__ out) {
    int g = blockIdx.x;
    int start = ptr[g], end = ptr[g + 1];
    int lane  = threadIdx.x & 63;
    int chunk = threadIdx.x >> 6;
    float acc = 0.0f;
    for (int r = start + chunk; r < end; r += 4)
        acc += H[(size_t)r * D + lane];
    __shared__ float tmp[4][64];
    tmp[chunk][lane] = acc;
    __syncthreads();
    if (threadIdx.x < 64) {
        float s = tmp[0][lane] + tmp[1][lane] + tmp[2][lane] + tmp[3][lane];
        out[g * D + lane] = s / (float)(end - start);
    }
}

extern "C" void kernel_launch(void* const* d_in, const int* in_sizes, int n_in,
                              void* d_out, int out_size, void* d_ws, size_t ws_size,
                              hipStream_t stream) {
    const float* x   = (const float*)d_in[0];
    const int*   ei  = (const int*)d_in[1];
    const int*   src = ei;
    const int*   dst = ei + N_EDGES;
    const int*   ptr = (const int*)d_in[2];
    const float* W1  = (const float*)d_in[3];
    const float* b1  = (const float*)d_in[4];
    const float* W2  = (const float*)d_in[5];
    const float* b2  = (const float*)d_in[6];
    const float* Wf  = (const float*)d_in[7];
    const float* bfp = (const float*)d_in[8];
    float* out = (float*)d_out;

    // workspace layout (4-byte units)
    int*   cnt       = (int*)d_ws;                  // 100352
    int*   row_start = cnt + 100352;                // 100352 (N+1 used)
    int*   sums      = row_start + 100352;          // 256
    int*   offs      = sums + 256;                  // 256
    int*   bcursor   = offs + 256;                  // 256
    float* P         = (float*)(bcursor + 256);     // 8192 (125*64 used)
    float* dis       = P + 8192;                    // 100352
    int*   csr       = (int*)(dis + 100352);        // 3200000
    float* A         = (float*)(csr + 3200000);     // 6400000
    float* B         = A + (size_t)N_NODES * D;     // 6400000
    int2*  pairs     = (int2*)A;                    // NB*CAP int2, aliases A+B

    // --- CSR build ---
    init_bcursor<<<1, 256, 0, stream>>>(bcursor);
    bucket_scatter<<<NB, 256, 0, stream>>>(src, dst, bcursor, pairs);
    bucket_hist<<<NB, 256, 0, stream>>>(pairs, bcursor, cnt, dis);
    scan1_kernel<<<NB, 256, 0, stream>>>(cnt, sums);
    scan2_kernel<<<1, 256, 0, stream>>>(sums, offs, row_start);
    scan3_kernel<<<NB, 256, 0, stream>>>(cnt, offs, row_start);
    bucket_fill<<<NB, 512, 0, stream>>>(pairs, bcursor, row_start, csr);

    const int grid4 = (N_NODES + 3) / 4;   // gemm: 4 rows/block; gather: 4 waves/block

    // layer 1: A = x @ W1 ; B = relu(gather(A) + A*dis^2 + b1)
    gemm_kernel<<<grid4, 256, 0, stream>>>(x, W1, nullptr, A, N_NODES);
    gather_kernel<<<grid4, 256, 0, stream>>>(A, csr, row_start, dis, b1, B, 1);

    // layer 2
    gemm_kernel<<<grid4, 256, 0, stream>>>(B, W2, nullptr, A, N_NODES);
    gather_kernel<<<grid4, 256, 0, stream>>>(A, csr, row_start, dis, b2, B, 1);

    // head: pool first (mean commutes with linear head), then tiny GEMM
    pool_kernel<<<N_GRAPHS, 256, 0, stream>>>(B, ptr, P);
    gemm_kernel<<<(N_GRAPHS + 3) / 4, 256, 0, stream>>>(P, Wf, bfp, out, N_GRAPHS);
}